// Round 22
// baseline (46.299 us; speedup 1.0000x reference)
//
#include <hip/hip_runtime.h>
#include <cstddef>

// Shapes: B=4, H=W=D=16, C=32, N=4096, Dout=13; out (4,16,16,13,32) f32.

typedef float f32x4 __attribute__((ext_vector_type(4)));
typedef short s16x8 __attribute__((ext_vector_type(8)));

#define SQRT_LOG2E 1.2011224087864498f   // xb scaled so QK^T lands in exp2 domain
#define C2SHIFT    57.70780163555854f    // 40*log2(e)

// HW packed f32->bf16. Used UNIFORMLY (xb, xtf, gram frags, P-pack): within-
// pair lo/hi permutation cancels in every MFMA contraction.
__device__ inline unsigned cvtpk(float a, float b) {
  unsigned r;
  asm("v_cvt_pk_bf16_f32 %0, %1, %2" : "=v"(r) : "v"(a), "v"(b));
  return r;
}

// ---------------------------------------------------------------------------
// K1: blocks 0..255 = prep (xb, xtf); blocks 256..287 = Gram partials from x
// (independent groups, one launch). partials -> pG/pS. (R21-proven verbatim.)
// ---------------------------------------------------------------------------
__global__ __launch_bounds__(256) void k_prepgram(
    const float* __restrict__ x, ushort* __restrict__ xb, ushort* __restrict__ xtf,
    float* __restrict__ pG, float* __restrict__ pS)
{
  int bx = blockIdx.x, tid = threadIdx.x;
  if (bx < 256) {
    int t = bx * 256 + tid;                        // 0..65535
    const float4* xs = (const float4*)x;
    float4 v0 = xs[2 * t], v1 = xs[2 * t + 1];
    uint4 o;
    o.x = cvtpk(v0.x * SQRT_LOG2E, v0.y * SQRT_LOG2E);
    o.y = cvtpk(v0.z * SQRT_LOG2E, v0.w * SQRT_LOG2E);
    o.z = cvtpk(v1.x * SQRT_LOG2E, v1.y * SQRT_LOG2E);
    o.w = cvtpk(v1.z * SQRT_LOG2E, v1.w * SQRT_LOG2E);
    ((uint4*)xb)[t] = o;

    int b = t >> 14, r2 = t & 16383;
    int ktile = r2 >> 7, r3 = r2 & 127;
    int h = r3 >> 6, lane = r3 & 63;
    int g = lane >> 4, c = h * 16 + (lane & 15);
    const float* src = x + (((size_t)b * 4096 + ktile * 32 + 8 * g) * 32 + c);
    float w[8];
#pragma unroll
    for (int j = 0; j < 8; ++j) w[j] = src[(size_t)j * 32];
    uint4 u;
    u.x = cvtpk(w[0], w[1]); u.y = cvtpk(w[2], w[3]);
    u.z = cvtpk(w[4], w[5]); u.w = cvtpk(w[6], w[7]);
    ((uint4*)xtf)[(size_t)((b * 128 + ktile) * 2 + h) * 64 + lane] = u;
    return;
  }

  int gb = bx - 256;
  int b = gb >> 3, ks = gb & 7;
  int wid = tid >> 6, lane = tid & 63;
  int g = lane >> 4, c16 = lane & 15;
  f32x4 z = {0.f, 0.f, 0.f, 0.f};
  f32x4 G00 = z, G01 = z, G10 = z, G11 = z, s0 = z, s1 = z;
  s16x8 ones;
#pragma unroll
  for (int j = 0; j < 8; ++j) ones[j] = (short)0x3F80;
  int t0 = ks * 16 + wid * 4;
  for (int t = t0; t < t0 + 4; ++t) {
    s16x8 fr0, fr1;
    {
      const float* src = x + (((size_t)b * 4096 + t * 32 + 8 * g) * 32 + c16);
      float w[8];
#pragma unroll
      for (int j = 0; j < 8; ++j) w[j] = src[(size_t)j * 32];
      uint4 u2 = make_uint4(cvtpk(w[0], w[1]), cvtpk(w[2], w[3]),
                            cvtpk(w[4], w[5]), cvtpk(w[6], w[7]));
      fr0 = __builtin_bit_cast(s16x8, u2);
    }
    {
      const float* src = x + (((size_t)b * 4096 + t * 32 + 8 * g) * 32 + 16 + c16);
      float w[8];
#pragma unroll
      for (int j = 0; j < 8; ++j) w[j] = src[(size_t)j * 32];
      uint4 u2 = make_uint4(cvtpk(w[0], w[1]), cvtpk(w[2], w[3]),
                            cvtpk(w[4], w[5]), cvtpk(w[6], w[7]));
      fr1 = __builtin_bit_cast(s16x8, u2);
    }
    G00 = __builtin_amdgcn_mfma_f32_16x16x32_bf16(fr0, fr0, G00, 0, 0, 0);
    G01 = __builtin_amdgcn_mfma_f32_16x16x32_bf16(fr0, fr1, G01, 0, 0, 0);
    G10 = __builtin_amdgcn_mfma_f32_16x16x32_bf16(fr1, fr0, G10, 0, 0, 0);
    G11 = __builtin_amdgcn_mfma_f32_16x16x32_bf16(fr1, fr1, G11, 0, 0, 0);
    s0  = __builtin_amdgcn_mfma_f32_16x16x32_bf16(fr0, ones, s0, 0, 0, 0);
    s1  = __builtin_amdgcn_mfma_f32_16x16x32_bf16(fr1, ones, s1, 0, 0, 0);
  }
  int p = gb * 4 + wid;                            // b-major, 0..127
  float* pg = pG + (size_t)p * 1024;
#pragma unroll
  for (int hr = 0; hr < 2; ++hr)
#pragma unroll
    for (int hc = 0; hc < 2; ++hc) {
      f32x4 v = hr ? (hc ? G11 : G10) : (hc ? G01 : G00);
#pragma unroll
      for (int r = 0; r < 4; ++r)
        pg[(16 * hr + 4 * g + r) * 32 + 16 * hc + c16] = v[r];
    }
  if (c16 == 0) {
#pragma unroll
    for (int hr = 0; hr < 2; ++hr) {
      f32x4 v = hr ? s1 : s0;
#pragma unroll
      for (int r = 0; r < 4; ++r) pS[p * 32 + 16 * hr + 4 * g + r] = v[r];
    }
  }
}

// ---------------------------------------------------------------------------
// K2: fused flash + PER-BLOCK REDUNDANT ALGEBRA + conv. Flash loop is R18/R21
// verbatim. After combine, each block reduces pG/pS for its b and computes
// the folded position-branch weights DIRECTLY INTO conv-weight LDS (ph2.wp)
// and bias into bpS — k_alg launch deleted; w2/b2 never touch global memory.
// grid (64 rowgroups, 4 b) x 1024 thr.
// ---------------------------------------------------------------------------
union BigSh {
  char stage[4][2][8192];   // [kh][buf] : 4KB kf rows (swizzled) + 4KB xtf
  struct { f32x4 pO0[3][4][64]; f32x4 pO1[3][4][64]; float pL[3][4][64]; } ph1;
  struct { float4 wc[1024]; float4 wp[1024]; } ph2;
};

__global__ __launch_bounds__(1024) void k_fused(
    const ushort* __restrict__ xb, const ushort* __restrict__ xtf,
    const float* __restrict__ x, const float* __restrict__ beta,
    const float* __restrict__ pG, const float* __restrict__ pS,
    const float* __restrict__ wq, const float* __restrict__ bq,
    const float* __restrict__ wk, const float* __restrict__ bk,
    const float* __restrict__ wv, const float* __restrict__ bv,
    const float* __restrict__ gamma,
    const float* __restrict__ wch, const float* __restrict__ bch,
    const float* __restrict__ wpos, const float* __restrict__ bpos,
    float* __restrict__ out)
{
  __shared__ BigSh u;
  __shared__ float sS[64][32];
  __shared__ float bcS[32], bpS[32];
  // algebra scratch (separate; used only after the flash loop)
  __shared__ float aG[1024], as_[32], at1[1024], aatt[1024], aM[1024], amv[32];
  __shared__ float awq[1024], awk[1024], awv[1024], awpo[4096];
  int rg = blockIdx.x, b = blockIdx.y, tid = threadIdx.x;
  if (tid < 32) bcS[tid] = bch[tid];

  int wid = tid >> 6, lane = tid & 63, g = lane >> 4, c16 = lane & 15;
  int wid2 = wid & 3, kh = wid >> 2;               // row-subgroup, key-quarter
  int qw = rg * 64 + wid2 * 16;
  const ushort* xbb = xb + ((size_t)b << 17);
  const ushort* xtb = xtf + (size_t)b * 131072;

  s16x8 qA = *(const s16x8*)(xbb + (qw + c16) * 32 + 8 * g);
  f32x4 z = {0.f, 0.f, 0.f, 0.f};
  f32x4 minit = {-C2SHIFT, -C2SHIFT, -C2SHIFT, -C2SHIFT};
  f32x4 oA0 = z, oA1 = z, lac = z;
  s16x8 ones;
#pragma unroll
  for (int j = 0; j < 8; ++j) ones[j] = (short)0x3F80;
  int kap = ((c16 >> 2) << 3) + (c16 & 3);         // kappa(c16)
  int k0 = kh * 1024;

  int wtid = wid2 * 64 + lane;                     // 0..255
  int srow = wtid >> 2, sslot = wtid & 3;
  int wslot = (sslot ^ (srow & 3)) << 4;
  int rslot = (g ^ (c16 & 3)) << 4;
  uint4 rkf, rxt;

#define LOADG(t) {                                                             \
    int kt = k0 + (t) * 64;                                                    \
    rkf = *(const uint4*)(xbb + (size_t)(kt + srow) * 32 + sslot * 8);         \
    rxt = *(const uint4*)(xtb + (size_t)(kt >> 5) * 1024 + wtid * 8);          \
  }
#define WRITES(bi) {                                                           \
    char* dst = u.stage[kh][bi];                                               \
    *(uint4*)(dst + srow * 64 + wslot) = rkf;                                  \
    *(uint4*)(dst + 4096 + wtid * 16) = rxt;                                   \
  }

  LOADG(0)
  WRITES(0)
  __syncthreads();

  for (int t = 0; t < 16; ++t) {
    if (t < 15) LOADG(t + 1)
    {
      const char* buf = u.stage[kh][t & 1];
      s16x8 kf0a = *(const s16x8*)(buf + kap * 64 + rslot);
      s16x8 kf1a = *(const s16x8*)(buf + (kap + 4) * 64 + rslot);
      s16x8 kf0b = *(const s16x8*)(buf + (32 + kap) * 64 + rslot);
      s16x8 kf1b = *(const s16x8*)(buf + (36 + kap) * 64 + rslot);
      const char* xt = buf + 4096 + lane * 16;
      s16x8 a0a = *(const s16x8*)(xt);
      s16x8 a1a = *(const s16x8*)(xt + 1024);
      s16x8 a0b = *(const s16x8*)(xt + 2048);
      s16x8 a1b = *(const s16x8*)(xt + 3072);

      __builtin_amdgcn_s_setprio(1);
      f32x4 e0 = __builtin_amdgcn_mfma_f32_16x16x32_bf16(kf0a, qA, minit, 0, 0, 0);
      f32x4 e1 = __builtin_amdgcn_mfma_f32_16x16x32_bf16(kf1a, qA, minit, 0, 0, 0);
      f32x4 e2 = __builtin_amdgcn_mfma_f32_16x16x32_bf16(kf0b, qA, minit, 0, 0, 0);
      f32x4 e3 = __builtin_amdgcn_mfma_f32_16x16x32_bf16(kf1b, qA, minit, 0, 0, 0);
      __builtin_amdgcn_s_setprio(0);
      f32x4 p0, p1, p2, p3;
#pragma unroll
      for (int r = 0; r < 4; ++r) {
        p0[r] = __builtin_amdgcn_exp2f(e0[r]);
        p1[r] = __builtin_amdgcn_exp2f(e1[r]);
        p2[r] = __builtin_amdgcn_exp2f(e2[r]);
        p3[r] = __builtin_amdgcn_exp2f(e3[r]);
      }
      uint4 uA = make_uint4(cvtpk(p0[0], p0[1]), cvtpk(p0[2], p0[3]),
                            cvtpk(p1[0], p1[1]), cvtpk(p1[2], p1[3]));
      uint4 uB = make_uint4(cvtpk(p2[0], p2[1]), cvtpk(p2[2], p2[3]),
                            cvtpk(p3[0], p3[1]), cvtpk(p3[2], p3[3]));
      s16x8 fpa = __builtin_bit_cast(s16x8, uA);
      s16x8 fpb = __builtin_bit_cast(s16x8, uB);

      __builtin_amdgcn_s_setprio(1);
      oA0 = __builtin_amdgcn_mfma_f32_16x16x32_bf16(a0a, fpa, oA0, 0, 0, 0);
      oA1 = __builtin_amdgcn_mfma_f32_16x16x32_bf16(a1a, fpa, oA1, 0, 0, 0);
      lac = __builtin_amdgcn_mfma_f32_16x16x32_bf16(ones, fpa, lac, 0, 0, 0);
      oA0 = __builtin_amdgcn_mfma_f32_16x16x32_bf16(a0b, fpb, oA0, 0, 0, 0);
      oA1 = __builtin_amdgcn_mfma_f32_16x16x32_bf16(a1b, fpb, oA1, 0, 0, 0);
      lac = __builtin_amdgcn_mfma_f32_16x16x32_bf16(ones, fpb, lac, 0, 0, 0);
      __builtin_amdgcn_s_setprio(0);
    }
    if (t < 15) WRITES((t + 1) & 1)
    __syncthreads();
  }
#undef LOADG
#undef WRITES

  // combine 4 key-quarters (additive: fixed softmax shift)
  if (kh != 0) {
    u.ph1.pO0[kh - 1][wid2][lane] = oA0;
    u.ph1.pO1[kh - 1][wid2][lane] = oA1;
    u.ph1.pL[kh - 1][wid2][lane] = lac[0];
  }
  __syncthreads();
  if (kh == 0) {
    float L = lac[0];
    f32x4 t0 = oA0, t1 = oA1;
#pragma unroll
    for (int q = 0; q < 3; ++q) {
      f32x4 q0 = u.ph1.pO0[q][wid2][lane], q1 = u.ph1.pO1[q][wid2][lane];
      L += u.ph1.pL[q][wid2][lane];
#pragma unroll
      for (int r = 0; r < 4; ++r) { t0[r] += q0[r]; t1[r] += q1[r]; }
    }
    float sc = beta[0] / L;
    int rloc = wid2 * 16 + c16;
    f32x4 v0, v1;
#pragma unroll
    for (int r = 0; r < 4; ++r) { v0[r] = t0[r] * sc; v1[r] = t1[r] * sc; }
    *(f32x4*)&sS[rloc][4 * g] = v0;
    *(f32x4*)&sS[rloc][16 + 4 * g] = v1;
  }
  // stage algebra weights while combine finishes (no dependency)
  if (tid < 256)      ((float4*)awq)[tid] = ((const float4*)wq)[tid];
  else if (tid < 512) ((float4*)awk)[tid - 256] = ((const float4*)wk)[tid - 256];
  else if (tid < 768) ((float4*)awv)[tid - 512] = ((const float4*)wv)[tid - 512];
  ((float4*)awpo)[tid] = ((const float4*)wpos)[tid];
  {
    const float* pg = pG + (size_t)b * 32 * 1024 + tid;
    float g0 = 0.f;
#pragma unroll
    for (int j = 0; j < 32; ++j) g0 += pg[(size_t)j * 1024];
    aG[tid] = g0;
  }
  if (tid < 32) {
    const float* ps = pS + b * 32 * 32 + tid;
    float sv = 0.f;
#pragma unroll
    for (int j = 0; j < 32; ++j) sv += ps[j * 32];
    as_[tid] = sv;
  }
  __syncthreads();

  // ---- algebra (k_alg body; results -> ph2.wp and bpS, no global) ----
  {
    int c = tid >> 5, f = tid & 31;
    float t = 0.f;
#pragma unroll
    for (int j = 0; j < 32; ++j) t = fmaf(aG[c * 32 + j], awk[j * 32 + f], t);
    at1[tid] = t;
    __syncthreads();
    float swk = 0.f, swq = 0.f;
#pragma unroll
    for (int j = 0; j < 32; ++j) {
      swk = fmaf(as_[j], awk[j * 32 + f], swk);
      swq = fmaf(as_[j], awq[j * 32 + c], swq);
    }
    float e = 0.f;
#pragma unroll
    for (int i = 0; i < 32; ++i) e = fmaf(awq[i * 32 + c], at1[i * 32 + f], e);
    e += bq[c] * (swk + 4096.f * bk[f]) + swq * bk[f];
    float m_ = e;
    for (int off = 16; off; off >>= 1) m_ = fmaxf(m_, __shfl_xor(m_, off, 32));
    float pr = __expf(e - m_);
    float sum = pr;
    for (int off = 16; off; off >>= 1) sum += __shfl_xor(sum, off, 32);
    aatt[tid] = pr / sum;                          // att[c][f]
    __syncthreads();
    float mm = 0.f;
#pragma unroll
    for (int j = 0; j < 32; ++j) mm = fmaf(awv[c * 32 + j], aatt[f * 32 + j], mm);
    aM[c * 32 + f] = mm;
    if (c == 0) {
      float mv = 0.f;
#pragma unroll
      for (int j = 0; j < 32; ++j) mv = fmaf(bv[j], aatt[f * 32 + j], mv);
      amv[f] = mv;
    }
    __syncthreads();
    float gam = gamma[0];
    float* wpf = (float*)u.ph2.wp;                 // ph1 dead; write folded wts
    for (int kd = 0; kd < 4; ++kd) {
      float acc = 0.f;
#pragma unroll
      for (int j = 0; j < 32; ++j)
        acc = fmaf(aM[c * 32 + j], awpo[(kd * 32 + j) * 32 + f], acc);
      wpf[(kd * 32 + c) * 32 + f] = gam * acc + awpo[(kd * 32 + c) * 32 + f];
    }
    if (c == 0) {
      float acc = 0.f;
#pragma unroll
      for (int kd = 0; kd < 4; ++kd)
#pragma unroll
        for (int j = 0; j < 32; ++j)
          acc = fmaf(amv[j], awpo[(kd * 32 + j) * 32 + tid], acc);
      bpS[tid] = gam * acc + bpos[tid];
    }
  }
  u.ph2.wc[tid] = ((const float4*)wch)[tid];
  __syncthreads();

  // conv3d(1,1,4) + relu both branches; 416 active threads (52 rows x 8 fq).
  if (tid < 416) {
    int row2 = tid >> 3, fq = tid & 7;
    int hw_l = row2 / 13, dout = row2 % 13;
    int rbase = hw_l * 16 + dout;
    size_t xrow = ((size_t)b * 4096 + (size_t)(rg * 4 + hw_l) * 16 + dout) * 32;
    float accC[4], accP[4];
#pragma unroll
    for (int j = 0; j < 4; ++j) { accC[j] = bcS[fq * 4 + j]; accP[j] = bpS[fq * 4 + j]; }
    for (int kd = 0; kd < 4; ++kd) {
      const float4* xr4 = (const float4*)(x + xrow + (size_t)kd * 32);
      const float* srow2 = sS[rbase + kd];
#pragma unroll
      for (int c4 = 0; c4 < 8; ++c4) {
        float4 xv = xr4[c4];
#pragma unroll
        for (int e = 0; e < 4; ++e) {
          float xve = (e == 0 ? xv.x : e == 1 ? xv.y : e == 2 ? xv.z : xv.w);
          float cve = srow2[4 * c4 + e] + xve;
          int wbase = (kd * 32 + 4 * c4 + e) * 8 + fq;
          float4 w1 = u.ph2.wc[wbase];
          accC[0] = fmaf(cve, w1.x, accC[0]);
          accC[1] = fmaf(cve, w1.y, accC[1]);
          accC[2] = fmaf(cve, w1.z, accC[2]);
          accC[3] = fmaf(cve, w1.w, accC[3]);
          float4 w2v = u.ph2.wp[wbase];
          accP[0] = fmaf(xve, w2v.x, accP[0]);
          accP[1] = fmaf(xve, w2v.y, accP[1]);
          accP[2] = fmaf(xve, w2v.z, accP[2]);
          accP[3] = fmaf(xve, w2v.w, accP[3]);
        }
      }
    }
    int gid = b * 3328 + (rg * 4 + hw_l) * 13 + dout;
    float* orow = out + (size_t)gid * 32 + fq * 4;
    float4 o;
    o.x = fmaxf(accC[0], 0.f) + fmaxf(accP[0], 0.f);
    o.y = fmaxf(accC[1], 0.f) + fmaxf(accP[1], 0.f);
    o.z = fmaxf(accC[2], 0.f) + fmaxf(accP[2], 0.f);
    o.w = fmaxf(accC[3], 0.f) + fmaxf(accP[3], 0.f);
    *(float4*)orow = o;
  }
}

extern "C" void kernel_launch(void* const* d_in, const int* in_sizes, int n_in,
                              void* d_out, int out_size, void* d_ws, size_t ws_size,
                              hipStream_t stream)
{
  const float* x     = (const float*)d_in[0];
  const float* beta  = (const float*)d_in[1];
  const float* wq    = (const float*)d_in[2];
  const float* bq    = (const float*)d_in[3];
  const float* wk    = (const float*)d_in[4];
  const float* bk    = (const float*)d_in[5];
  const float* wv    = (const float*)d_in[6];
  const float* bv    = (const float*)d_in[7];
  const float* gamma = (const float*)d_in[8];
  const float* wch   = (const float*)d_in[9];
  const float* bch   = (const float*)d_in[10];
  const float* wpos  = (const float*)d_in[11];
  const float* bpos  = (const float*)d_in[12];
  float* out = (float*)d_out;
  float* ws  = (float*)d_ws;

  ushort* xb  = (ushort*)(ws + 0);        // 512 KB
  ushort* xtf = (ushort*)(ws + 262144);   // 512 KB
  float*  pG  = ws + 524288;              // 512 KB
  float*  pS  = ws + 655360;              // 16 KB

  hipLaunchKernelGGL(k_prepgram, dim3(288),   dim3(256),  0, stream,
                     x, xb, xtf, pG, pS);
  hipLaunchKernelGGL(k_fused,    dim3(64, 4), dim3(1024), 0, stream,
                     xb, xtf, x, beta, pG, pS,
                     wq, bq, wk, bk, wv, bv, gamma, wch, bch, wpos, bpos, out);
}

// Round 23
// 41.562 us; speedup vs baseline: 1.1140x; 1.1140x over previous
//
#include <hip/hip_runtime.h>
#include <cstddef>

// Shapes: B=4, H=W=D=16, C=32, N=4096, Dout=13; out (4,16,16,13,32) f32.

typedef float f32x4 __attribute__((ext_vector_type(4)));
typedef short s16x8 __attribute__((ext_vector_type(8)));

#define SQRT_LOG2E 1.2011224087864498f   // xb scaled so QK^T lands in exp2 domain
#define C2SHIFT    57.70780163555854f    // 40*log2(e)

// HW packed f32->bf16. Used UNIFORMLY (xb, xtf, gram frags, P-pack): within-
// pair lo/hi permutation cancels in every MFMA contraction.
__device__ inline unsigned cvtpk(float a, float b) {
  unsigned r;
  asm("v_cvt_pk_bf16_f32 %0, %1, %2" : "=v"(r) : "v"(a), "v"(b));
  return r;
}

// ---------------------------------------------------------------------------
// K1: blocks 0..255 = prep (xb, xtf); blocks 256..287 = Gram partials from x
// (independent groups, one launch). partials -> pG/pS. (R21-proven verbatim.)
// ---------------------------------------------------------------------------
__global__ __launch_bounds__(256) void k_prepgram(
    const float* __restrict__ x, ushort* __restrict__ xb, ushort* __restrict__ xtf,
    float* __restrict__ pG, float* __restrict__ pS)
{
  int bx = blockIdx.x, tid = threadIdx.x;
  if (bx < 256) {
    int t = bx * 256 + tid;                        // 0..65535
    const float4* xs = (const float4*)x;
    float4 v0 = xs[2 * t], v1 = xs[2 * t + 1];
    uint4 o;
    o.x = cvtpk(v0.x * SQRT_LOG2E, v0.y * SQRT_LOG2E);
    o.y = cvtpk(v0.z * SQRT_LOG2E, v0.w * SQRT_LOG2E);
    o.z = cvtpk(v1.x * SQRT_LOG2E, v1.y * SQRT_LOG2E);
    o.w = cvtpk(v1.z * SQRT_LOG2E, v1.w * SQRT_LOG2E);
    ((uint4*)xb)[t] = o;

    int b = t >> 14, r2 = t & 16383;
    int ktile = r2 >> 7, r3 = r2 & 127;
    int h = r3 >> 6, lane = r3 & 63;
    int g = lane >> 4, c = h * 16 + (lane & 15);
    const float* src = x + (((size_t)b * 4096 + ktile * 32 + 8 * g) * 32 + c);
    float w[8];
#pragma unroll
    for (int j = 0; j < 8; ++j) w[j] = src[(size_t)j * 32];
    uint4 u;
    u.x = cvtpk(w[0], w[1]); u.y = cvtpk(w[2], w[3]);
    u.z = cvtpk(w[4], w[5]); u.w = cvtpk(w[6], w[7]);
    ((uint4*)xtf)[(size_t)((b * 128 + ktile) * 2 + h) * 64 + lane] = u;
    return;
  }

  int gb = bx - 256;
  int b = gb >> 3, ks = gb & 7;
  int wid = tid >> 6, lane = tid & 63;
  int g = lane >> 4, c16 = lane & 15;
  f32x4 z = {0.f, 0.f, 0.f, 0.f};
  f32x4 G00 = z, G01 = z, G10 = z, G11 = z, s0 = z, s1 = z;
  s16x8 ones;
#pragma unroll
  for (int j = 0; j < 8; ++j) ones[j] = (short)0x3F80;
  int t0 = ks * 16 + wid * 4;
  for (int t = t0; t < t0 + 4; ++t) {
    s16x8 fr0, fr1;
    {
      const float* src = x + (((size_t)b * 4096 + t * 32 + 8 * g) * 32 + c16);
      float w[8];
#pragma unroll
      for (int j = 0; j < 8; ++j) w[j] = src[(size_t)j * 32];
      uint4 u2 = make_uint4(cvtpk(w[0], w[1]), cvtpk(w[2], w[3]),
                            cvtpk(w[4], w[5]), cvtpk(w[6], w[7]));
      fr0 = __builtin_bit_cast(s16x8, u2);
    }
    {
      const float* src = x + (((size_t)b * 4096 + t * 32 + 8 * g) * 32 + 16 + c16);
      float w[8];
#pragma unroll
      for (int j = 0; j < 8; ++j) w[j] = src[(size_t)j * 32];
      uint4 u2 = make_uint4(cvtpk(w[0], w[1]), cvtpk(w[2], w[3]),
                            cvtpk(w[4], w[5]), cvtpk(w[6], w[7]));
      fr1 = __builtin_bit_cast(s16x8, u2);
    }
    G00 = __builtin_amdgcn_mfma_f32_16x16x32_bf16(fr0, fr0, G00, 0, 0, 0);
    G01 = __builtin_amdgcn_mfma_f32_16x16x32_bf16(fr0, fr1, G01, 0, 0, 0);
    G10 = __builtin_amdgcn_mfma_f32_16x16x32_bf16(fr1, fr0, G10, 0, 0, 0);
    G11 = __builtin_amdgcn_mfma_f32_16x16x32_bf16(fr1, fr1, G11, 0, 0, 0);
    s0  = __builtin_amdgcn_mfma_f32_16x16x32_bf16(fr0, ones, s0, 0, 0, 0);
    s1  = __builtin_amdgcn_mfma_f32_16x16x32_bf16(fr1, ones, s1, 0, 0, 0);
  }
  int p = gb * 4 + wid;                            // b-major, 0..127
  float* pg = pG + (size_t)p * 1024;
#pragma unroll
  for (int hr = 0; hr < 2; ++hr)
#pragma unroll
    for (int hc = 0; hc < 2; ++hc) {
      f32x4 v = hr ? (hc ? G11 : G10) : (hc ? G01 : G00);
#pragma unroll
      for (int r = 0; r < 4; ++r)
        pg[(16 * hr + 4 * g + r) * 32 + 16 * hc + c16] = v[r];
    }
  if (c16 == 0) {
#pragma unroll
    for (int hr = 0; hr < 2; ++hr) {
      f32x4 v = hr ? s1 : s0;
#pragma unroll
      for (int r = 0; r < 4; ++r) pS[p * 32 + 16 * hr + 4 * g + r] = v[r];
    }
  }
}

// ---------------------------------------------------------------------------
// K2: algebra. Parallel reduce of partials + stage B with LDS weights.
// att padded to stride 33 (fixes 32-way bank conflict on att[f][j] reads).
// 4 blocks x 1024 thr.
// ---------------------------------------------------------------------------
__global__ __launch_bounds__(1024) void k_alg(
    const float* __restrict__ pG, const float* __restrict__ pS,
    const float* __restrict__ wq, const float* __restrict__ bq,
    const float* __restrict__ wk, const float* __restrict__ bk,
    const float* __restrict__ wv, const float* __restrict__ bv,
    const float* __restrict__ gamma,
    const float* __restrict__ wpos, const float* __restrict__ bpos,
    float* __restrict__ w2, float* __restrict__ b2)
{
  __shared__ float G[1024], s[32], t1[1024], att[32 * 33], M[1024], mvec[32];
  __shared__ float wqS[1024], wkS[1024], wvS[1024], wpoS[4096];
  int b = blockIdx.x, tid = threadIdx.x;
  if (tid < 256)      ((float4*)wqS)[tid] = ((const float4*)wq)[tid];
  else if (tid < 512) ((float4*)wkS)[tid - 256] = ((const float4*)wk)[tid - 256];
  else if (tid < 768) ((float4*)wvS)[tid - 512] = ((const float4*)wv)[tid - 512];
  ((float4*)wpoS)[tid] = ((const float4*)wpos)[tid];

  {
    const float* pg = pG + (size_t)b * 32 * 1024 + tid;
    float g0 = 0.f;
#pragma unroll
    for (int j = 0; j < 32; ++j) g0 += pg[(size_t)j * 1024];
    G[tid] = g0;
  }
  if (tid < 32) {
    const float* ps = pS + b * 32 * 32 + tid;
    float sv = 0.f;
#pragma unroll
    for (int j = 0; j < 32; ++j) sv += ps[j * 32];
    s[tid] = sv;
  }
  __syncthreads();

  int c = tid >> 5, f = tid & 31;
  float t = 0.f;
#pragma unroll
  for (int j = 0; j < 32; ++j) t = fmaf(G[c * 32 + j], wkS[j * 32 + f], t);
  t1[tid] = t;
  __syncthreads();
  float swk = 0.f, swq = 0.f;
#pragma unroll
  for (int j = 0; j < 32; ++j) {
    swk = fmaf(s[j], wkS[j * 32 + f], swk);
    swq = fmaf(s[j], wqS[j * 32 + c], swq);
  }
  float e = 0.f;
#pragma unroll
  for (int i = 0; i < 32; ++i) e = fmaf(wqS[i * 32 + c], t1[i * 32 + f], e);
  e += bq[c] * (swk + 4096.f * bk[f]) + swq * bk[f];
  float m_ = e;
  for (int off = 16; off; off >>= 1) m_ = fmaxf(m_, __shfl_xor(m_, off, 32));
  float pr = __expf(e - m_);
  float sum = pr;
  for (int off = 16; off; off >>= 1) sum += __shfl_xor(sum, off, 32);
  att[c * 33 + f] = pr / sum;                      // att[c][f], padded stride
  __syncthreads();
  float mm = 0.f;
#pragma unroll
  for (int j = 0; j < 32; ++j) mm = fmaf(wvS[c * 32 + j], att[f * 33 + j], mm);
  M[c * 32 + f] = mm;
  if (c == 0) {
    float mv = 0.f;
#pragma unroll
    for (int j = 0; j < 32; ++j) mv = fmaf(bv[j], att[f * 33 + j], mv);
    mvec[f] = mv;
  }
  __syncthreads();
  float gam = gamma[0];
  for (int kd = 0; kd < 4; ++kd) {
    float acc = 0.f;
#pragma unroll
    for (int j = 0; j < 32; ++j)
      acc = fmaf(M[c * 32 + j], wpoS[(kd * 32 + j) * 32 + f], acc);
    w2[((b * 4 + kd) * 32 + c) * 32 + f] = gam * acc + wpoS[(kd * 32 + c) * 32 + f];
  }
  if (c == 0) {
    float acc = 0.f;
#pragma unroll
    for (int kd = 0; kd < 4; ++kd)
#pragma unroll
      for (int j = 0; j < 32; ++j)
        acc = fmaf(mvec[j], wpoS[(kd * 32 + j) * 32 + tid], acc);
    b2[b * 32 + tid] = gam * acc + bpos[tid];
  }
}

// ---------------------------------------------------------------------------
// K3: fused flash + conv (R18/R21-proven VERBATIM: 1024 thr, 16 waves = 4
// row-subgroups x 4 key-quarters, LDS double-buffered 64-key tiles, XOR-
// swizzled kf slots, stage union'd with combine/conv-weight LDS). grid (64,4).
// ---------------------------------------------------------------------------
union BigSh {
  char stage[4][2][8192];   // [kh][buf] : 4KB kf rows (swizzled) + 4KB xtf
  struct { f32x4 pO0[3][4][64]; f32x4 pO1[3][4][64]; float pL[3][4][64]; } ph1;
  struct { float4 wc[1024]; float4 wp[1024]; } ph2;
};

__global__ __launch_bounds__(1024) void k_fused(
    const ushort* __restrict__ xb, const ushort* __restrict__ xtf,
    const float* __restrict__ x, const float* __restrict__ beta,
    const float* __restrict__ wch, const float* __restrict__ bch,
    const float* __restrict__ w2, const float* __restrict__ b2,
    float* __restrict__ out)
{
  __shared__ BigSh u;
  __shared__ float sS[64][32];
  __shared__ float bcS[32], bpS[32];
  int rg = blockIdx.x, b = blockIdx.y, tid = threadIdx.x;
  if (tid < 32) { bcS[tid] = bch[tid]; bpS[tid] = b2[b * 32 + tid]; }

  int wid = tid >> 6, lane = tid & 63, g = lane >> 4, c16 = lane & 15;
  int wid2 = wid & 3, kh = wid >> 2;               // row-subgroup, key-quarter
  int qw = rg * 64 + wid2 * 16;
  const ushort* xbb = xb + ((size_t)b << 17);
  const ushort* xtb = xtf + (size_t)b * 131072;

  s16x8 qA = *(const s16x8*)(xbb + (qw + c16) * 32 + 8 * g);
  f32x4 z = {0.f, 0.f, 0.f, 0.f};
  f32x4 minit = {-C2SHIFT, -C2SHIFT, -C2SHIFT, -C2SHIFT};
  f32x4 oA0 = z, oA1 = z, lac = z;
  s16x8 ones;
#pragma unroll
  for (int j = 0; j < 8; ++j) ones[j] = (short)0x3F80;
  int kap = ((c16 >> 2) << 3) + (c16 & 3);         // kappa(c16)
  int k0 = kh * 1024;

  // staging identity within kh-group (4 waves = 256 threads)
  int wtid = wid2 * 64 + lane;                     // 0..255
  int srow = wtid >> 2, sslot = wtid & 3;
  int wslot = (sslot ^ (srow & 3)) << 4;           // swizzled kf byte slot
  int rslot = (g ^ (c16 & 3)) << 4;                // swizzled read slot
  uint4 rkf, rxt;

#define LOADG(t) {                                                             \
    int kt = k0 + (t) * 64;                                                    \
    rkf = *(const uint4*)(xbb + (size_t)(kt + srow) * 32 + sslot * 8);         \
    rxt = *(const uint4*)(xtb + (size_t)(kt >> 5) * 1024 + wtid * 8);          \
  }
#define WRITES(bi) {                                                           \
    char* dst = u.stage[kh][bi];                                               \
    *(uint4*)(dst + srow * 64 + wslot) = rkf;                                  \
    *(uint4*)(dst + 4096 + wtid * 16) = rxt;                                   \
  }

  LOADG(0)
  WRITES(0)
  __syncthreads();

  for (int t = 0; t < 16; ++t) {
    if (t < 15) LOADG(t + 1)
    {
      const char* buf = u.stage[kh][t & 1];
      s16x8 kf0a = *(const s16x8*)(buf + kap * 64 + rslot);
      s16x8 kf1a = *(const s16x8*)(buf + (kap + 4) * 64 + rslot);
      s16x8 kf0b = *(const s16x8*)(buf + (32 + kap) * 64 + rslot);
      s16x8 kf1b = *(const s16x8*)(buf + (36 + kap) * 64 + rslot);
      const char* xt = buf + 4096 + lane * 16;
      s16x8 a0a = *(const s16x8*)(xt);
      s16x8 a1a = *(const s16x8*)(xt + 1024);
      s16x8 a0b = *(const s16x8*)(xt + 2048);
      s16x8 a1b = *(const s16x8*)(xt + 3072);

      __builtin_amdgcn_s_setprio(1);
      f32x4 e0 = __builtin_amdgcn_mfma_f32_16x16x32_bf16(kf0a, qA, minit, 0, 0, 0);
      f32x4 e1 = __builtin_amdgcn_mfma_f32_16x16x32_bf16(kf1a, qA, minit, 0, 0, 0);
      f32x4 e2 = __builtin_amdgcn_mfma_f32_16x16x32_bf16(kf0b, qA, minit, 0, 0, 0);
      f32x4 e3 = __builtin_amdgcn_mfma_f32_16x16x32_bf16(kf1b, qA, minit, 0, 0, 0);
      __builtin_amdgcn_s_setprio(0);
      f32x4 p0, p1, p2, p3;
#pragma unroll
      for (int r = 0; r < 4; ++r) {
        p0[r] = __builtin_amdgcn_exp2f(e0[r]);
        p1[r] = __builtin_amdgcn_exp2f(e1[r]);
        p2[r] = __builtin_amdgcn_exp2f(e2[r]);
        p3[r] = __builtin_amdgcn_exp2f(e3[r]);
      }
      uint4 uA = make_uint4(cvtpk(p0[0], p0[1]), cvtpk(p0[2], p0[3]),
                            cvtpk(p1[0], p1[1]), cvtpk(p1[2], p1[3]));
      uint4 uB = make_uint4(cvtpk(p2[0], p2[1]), cvtpk(p2[2], p2[3]),
                            cvtpk(p3[0], p3[1]), cvtpk(p3[2], p3[3]));
      s16x8 fpa = __builtin_bit_cast(s16x8, uA);
      s16x8 fpb = __builtin_bit_cast(s16x8, uB);

      __builtin_amdgcn_s_setprio(1);
      oA0 = __builtin_amdgcn_mfma_f32_16x16x32_bf16(a0a, fpa, oA0, 0, 0, 0);
      oA1 = __builtin_amdgcn_mfma_f32_16x16x32_bf16(a1a, fpa, oA1, 0, 0, 0);
      lac = __builtin_amdgcn_mfma_f32_16x16x32_bf16(ones, fpa, lac, 0, 0, 0);
      oA0 = __builtin_amdgcn_mfma_f32_16x16x32_bf16(a0b, fpb, oA0, 0, 0, 0);
      oA1 = __builtin_amdgcn_mfma_f32_16x16x32_bf16(a1b, fpb, oA1, 0, 0, 0);
      lac = __builtin_amdgcn_mfma_f32_16x16x32_bf16(ones, fpb, lac, 0, 0, 0);
      __builtin_amdgcn_s_setprio(0);
    }
    if (t < 15) WRITES((t + 1) & 1)
    __syncthreads();
  }
#undef LOADG
#undef WRITES

  // combine 4 key-quarters (additive: fixed softmax shift)
  if (kh != 0) {
    u.ph1.pO0[kh - 1][wid2][lane] = oA0;
    u.ph1.pO1[kh - 1][wid2][lane] = oA1;
    u.ph1.pL[kh - 1][wid2][lane] = lac[0];
  }
  __syncthreads();
  if (kh == 0) {
    float L = lac[0];
    f32x4 t0 = oA0, t1 = oA1;
#pragma unroll
    for (int q = 0; q < 3; ++q) {
      f32x4 q0 = u.ph1.pO0[q][wid2][lane], q1 = u.ph1.pO1[q][wid2][lane];
      L += u.ph1.pL[q][wid2][lane];
#pragma unroll
      for (int r = 0; r < 4; ++r) { t0[r] += q0[r]; t1[r] += q1[r]; }
    }
    float sc = beta[0] / L;
    int rloc = wid2 * 16 + c16;
    f32x4 v0, v1;
#pragma unroll
    for (int r = 0; r < 4; ++r) { v0[r] = t0[r] * sc; v1[r] = t1[r] * sc; }
    *(f32x4*)&sS[rloc][4 * g] = v0;
    *(f32x4*)&sS[rloc][16 + 4 * g] = v1;
  }
  __syncthreads();
  u.ph2.wc[tid] = ((const float4*)wch)[tid];
  u.ph2.wp[tid] = ((const float4*)(w2 + (size_t)b * 4096))[tid];
  __syncthreads();

  if (tid < 416) {
    int row2 = tid >> 3, fq = tid & 7;
    int hw_l = row2 / 13, dout = row2 % 13;
    int rbase = hw_l * 16 + dout;
    size_t xrow = ((size_t)b * 4096 + (size_t)(rg * 4 + hw_l) * 16 + dout) * 32;
    float accC[4], accP[4];
#pragma unroll
    for (int j = 0; j < 4; ++j) { accC[j] = bcS[fq * 4 + j]; accP[j] = bpS[fq * 4 + j]; }
    for (int kd = 0; kd < 4; ++kd) {
      const float4* xr4 = (const float4*)(x + xrow + (size_t)kd * 32);
      const float* srow2 = sS[rbase + kd];
#pragma unroll
      for (int c4 = 0; c4 < 8; ++c4) {
        float4 xv = xr4[c4];
#pragma unroll
        for (int e = 0; e < 4; ++e) {
          float xve = (e == 0 ? xv.x : e == 1 ? xv.y : e == 2 ? xv.z : xv.w);
          float cve = srow2[4 * c4 + e] + xve;
          int wbase = (kd * 32 + 4 * c4 + e) * 8 + fq;
          float4 w1 = u.ph2.wc[wbase];
          accC[0] = fmaf(cve, w1.x, accC[0]);
          accC[1] = fmaf(cve, w1.y, accC[1]);
          accC[2] = fmaf(cve, w1.z, accC[2]);
          accC[3] = fmaf(cve, w1.w, accC[3]);
          float4 w2v = u.ph2.wp[wbase];
          accP[0] = fmaf(xve, w2v.x, accP[0]);
          accP[1] = fmaf(xve, w2v.y, accP[1]);
          accP[2] = fmaf(xve, w2v.z, accP[2]);
          accP[3] = fmaf(xve, w2v.w, accP[3]);
        }
      }
    }
    int gid = b * 3328 + (rg * 4 + hw_l) * 13 + dout;
    float* orow = out + (size_t)gid * 32 + fq * 4;
    float4 o;
    o.x = fmaxf(accC[0], 0.f) + fmaxf(accP[0], 0.f);
    o.y = fmaxf(accC[1], 0.f) + fmaxf(accP[1], 0.f);
    o.z = fmaxf(accC[2], 0.f) + fmaxf(accP[2], 0.f);
    o.w = fmaxf(accC[3], 0.f) + fmaxf(accP[3], 0.f);
    *(float4*)orow = o;
  }
}

extern "C" void kernel_launch(void* const* d_in, const int* in_sizes, int n_in,
                              void* d_out, int out_size, void* d_ws, size_t ws_size,
                              hipStream_t stream)
{
  const float* x     = (const float*)d_in[0];
  const float* beta  = (const float*)d_in[1];
  const float* wq    = (const float*)d_in[2];
  const float* bq    = (const float*)d_in[3];
  const float* wk    = (const float*)d_in[4];
  const float* bk    = (const float*)d_in[5];
  const float* wv    = (const float*)d_in[6];
  const float* bv    = (const float*)d_in[7];
  const float* gamma = (const float*)d_in[8];
  const float* wch   = (const float*)d_in[9];
  const float* bch   = (const float*)d_in[10];
  const float* wpos  = (const float*)d_in[11];
  const float* bpos  = (const float*)d_in[12];
  float* out = (float*)d_out;
  float* ws  = (float*)d_ws;

  ushort* xb  = (ushort*)(ws + 0);        // 512 KB
  ushort* xtf = (ushort*)(ws + 262144);   // 512 KB
  float*  w2  = ws + 524288;              // 64 KB
  float*  b2  = ws + 540672;              // 512 B
  float*  pG  = ws + 540800;              // 512 KB
  float*  pS  = ws + 671872;              // 16 KB

  hipLaunchKernelGGL(k_prepgram, dim3(288),   dim3(256),  0, stream,
                     x, xb, xtf, pG, pS);
  hipLaunchKernelGGL(k_alg,      dim3(4),     dim3(1024), 0, stream,
                     pG, pS, wq, bq, wk, bk, wv, bv, gamma, wpos, bpos, w2, b2);
  hipLaunchKernelGGL(k_fused,    dim3(64, 4), dim3(1024), 0, stream,
                     xb, xtf, x, beta, wch, bch, w2, b2, out);
}